// Round 1
// baseline (2244.003 us; speedup 1.0000x reference)
//
#include <hip/hip_runtime.h>
#include <math.h>

#define H 51
#define HP 52
#define NG 4
#define TSEEN 256
#define FUT 16
#define TTOT (TSEEN + FUT)
#define BPB 8          // batches per block (4 waves x 2)
#define THREADS 256
#define BATCH 2048

__device__ __forceinline__ float fast_rcp(float x) { return __builtin_amdgcn_rcpf(x); }

__device__ __forceinline__ float fast_sig(float x) {
  // 1/(1+e^-x); large |x| saturates cleanly (rcp(inf)=0)
  float e = __expf(-x);
  return fast_rcp(1.f + e);
}

__device__ __forceinline__ float fast_tanh(float x) {
  // overflow-safe: uses exp(-2|x|) in (0,1]
  float ax = fabsf(x);
  float e  = __expf(-2.f * ax);
  float r  = (1.f - e) * fast_rcp(1.f + e);
  return copysignf(r, x);
}

__launch_bounds__(THREADS, 1)
__global__ void lstm2_kernel(const float* __restrict__ inp,
                             const float* __restrict__ Wih1,
                             const float* __restrict__ bih1,
                             const float* __restrict__ Whh1,
                             const float* __restrict__ bhh1,
                             const float* __restrict__ Wih2,
                             const float* __restrict__ bih2,
                             const float* __restrict__ Whh2,
                             const float* __restrict__ bhh2,
                             const float* __restrict__ Wlin,
                             const float* __restrict__ blin,
                             float* __restrict__ out)
{
  __shared__ __align__(16) float W2h[NG * H * HP];   // 204 rows x 52 (padded)
  __shared__ __align__(16) float h1s[4][2][HP];      // per-wave, per-batch h1
  __shared__ __align__(16) float h2s[4][2][HP];
  __shared__ float xs[BPB * TSEEN];

  const int tid   = threadIdx.x;
  const int w     = tid >> 6;
  const int lane  = tid & 63;
  const int baseb = blockIdx.x * BPB;

  // ---- stage Whh2 into LDS (padded rows, pad = 0) ----
  for (int i = tid; i < NG * H * H; i += THREADS) {
    int r = i / H;
    int k = i - r * H;
    W2h[r * HP + k] = Whh2[i];
  }
  for (int r = tid; r < NG * H; r += THREADS) W2h[r * HP + H] = 0.f;

  // ---- stage this block's input rows ----
  for (int i = tid; i < BPB * TSEEN; i += THREADS) xs[i] = inp[baseb * TSEEN + i];

  // ---- zero h state (incl. pad slots) ----
  {
    float* p1 = &h1s[0][0][0];
    float* p2 = &h2s[0][0][0];
    for (int i = tid; i < 4 * 2 * HP; i += THREADS) { p1[i] = 0.f; p2[i] = 0.f; }
  }

  // ---- per-lane register-resident weights (rows j, j+51, j+102, j+153) ----
  const bool active = lane < H;
  const int  j = active ? lane : (H - 1);   // clamp keeps all addrs in-bounds

  float w1[NG][H], w2i[NG][H];
  float bs1[NG], bs2[NG], wi1[NG];
  #pragma unroll
  for (int g = 0; g < NG; ++g) {
    const int r = g * H + j;
    float b1v = bih1[r] + bhh1[r];
    float b2v = bih2[r] + bhh2[r];
    float w1v = Wih1[r];
    bs1[g] = active ? b1v : 0.f;
    bs2[g] = active ? b2v : 0.f;
    wi1[g] = active ? w1v : 0.f;
    #pragma unroll
    for (int k = 0; k < H; ++k) {
      float a = Whh1[r * H + k];
      float b = Wih2[r * H + k];
      w1[g][k]  = active ? a : 0.f;
      w2i[g][k] = active ? b : 0.f;
    }
  }
  const float wlin = active ? Wlin[j] : 0.f;
  const float bl   = blin[0];

  float c1[2] = {0.f, 0.f}, c2[2] = {0.f, 0.f};
  float fb[2] = {0.f, 0.f};   // autoregressive feedback

  __syncthreads();

  #pragma unroll 1
  for (int t = 0; t < TTOT; ++t) {
    float x0, x1;
    if (t < TSEEN) {
      x0 = xs[(2 * w) * TSEEN + t];
      x1 = xs[(2 * w + 1) * TSEEN + t];
    } else {
      x0 = fb[0];
      x1 = fb[1];
    }

    // ---------------- layer 1: gates = W_ih1*x + W_hh1*h1 + b ----------------
    float acc0[NG], acc1[NG];
    #pragma unroll
    for (int g = 0; g < NG; ++g) {
      acc0[g] = fmaf(wi1[g], x0, bs1[g]);
      acc1[g] = fmaf(wi1[g], x1, bs1[g]);
    }
    #pragma unroll
    for (int kc = 0; kc < 13; ++kc) {
      const float4 hA = *(const float4*)&h1s[w][0][kc * 4];
      const float4 hB = *(const float4*)&h1s[w][1][kc * 4];
      const float ha[4] = {hA.x, hA.y, hA.z, hA.w};
      const float hb[4] = {hB.x, hB.y, hB.z, hB.w};
      #pragma unroll
      for (int kk = 0; kk < 4; ++kk) {
        const int k = kc * 4 + kk;
        if (k < H) {
          #pragma unroll
          for (int g = 0; g < NG; ++g) {
            acc0[g] = fmaf(w1[g][k], ha[kk], acc0[g]);
            acc1[g] = fmaf(w1[g][k], hb[kk], acc1[g]);
          }
        }
      }
    }

    float h1n[2];
    {
      float i0 = fast_sig(acc0[0]), f0 = fast_sig(acc0[1]);
      float g0 = fast_tanh(acc0[2]), o0 = fast_sig(acc0[3]);
      c1[0] = fmaf(f0, c1[0], i0 * g0);
      h1n[0] = o0 * fast_tanh(c1[0]);
      float i1 = fast_sig(acc1[0]), f1 = fast_sig(acc1[1]);
      float g1 = fast_tanh(acc1[2]), o1 = fast_sig(acc1[3]);
      c1[1] = fmaf(f1, c1[1], i1 * g1);
      h1n[1] = o1 * fast_tanh(c1[1]);
    }
    if (active) {
      h1s[w][0][lane] = h1n[0];
      h1s[w][1][lane] = h1n[1];
    }
    __syncthreads();

    // ------------- layer 2: gates = W_ih2*h1 + W_hh2*h2 + b -------------
    #pragma unroll
    for (int g = 0; g < NG; ++g) { acc0[g] = bs2[g]; acc1[g] = bs2[g]; }
    #pragma unroll
    for (int kc = 0; kc < 13; ++kc) {
      const float4 p1A = *(const float4*)&h1s[w][0][kc * 4];
      const float4 p1B = *(const float4*)&h1s[w][1][kc * 4];
      const float4 p2A = *(const float4*)&h2s[w][0][kc * 4];
      const float4 p2B = *(const float4*)&h2s[w][1][kc * 4];
      const float h1a[4] = {p1A.x, p1A.y, p1A.z, p1A.w};
      const float h1b[4] = {p1B.x, p1B.y, p1B.z, p1B.w};
      const float h2a[4] = {p2A.x, p2A.y, p2A.z, p2A.w};
      const float h2b[4] = {p2B.x, p2B.y, p2B.z, p2B.w};
      float4 wr[NG];
      #pragma unroll
      for (int g = 0; g < NG; ++g)
        wr[g] = *(const float4*)&W2h[(g * H + j) * HP + kc * 4];
      const float wrf[NG][4] = {
        {wr[0].x, wr[0].y, wr[0].z, wr[0].w},
        {wr[1].x, wr[1].y, wr[1].z, wr[1].w},
        {wr[2].x, wr[2].y, wr[2].z, wr[2].w},
        {wr[3].x, wr[3].y, wr[3].z, wr[3].w},
      };
      #pragma unroll
      for (int kk = 0; kk < 4; ++kk) {
        const int k = kc * 4 + kk;
        #pragma unroll
        for (int g = 0; g < NG; ++g) {
          if (k < H) {
            acc0[g] = fmaf(w2i[g][k], h1a[kk], acc0[g]);
            acc1[g] = fmaf(w2i[g][k], h1b[kk], acc1[g]);
          }
          // pad column (k==51): W2h pad = 0, h2 pad = 0 -> adds 0
          acc0[g] = fmaf(wrf[g][kk], h2a[kk], acc0[g]);
          acc1[g] = fmaf(wrf[g][kk], h2b[kk], acc1[g]);
        }
      }
    }

    float h2n[2];
    {
      float i0 = fast_sig(acc0[0]), f0 = fast_sig(acc0[1]);
      float g0 = fast_tanh(acc0[2]), o0 = fast_sig(acc0[3]);
      c2[0] = fmaf(f0, c2[0], i0 * g0);
      h2n[0] = o0 * fast_tanh(c2[0]);
      float i1 = fast_sig(acc1[0]), f1 = fast_sig(acc1[1]);
      float g1 = fast_tanh(acc1[2]), o1 = fast_sig(acc1[3]);
      c2[1] = fmaf(f1, c2[1], i1 * g1);
      h2n[1] = o1 * fast_tanh(c2[1]);
    }

    // ------------- linear head + butterfly reduce over units -------------
    float oa = wlin * h2n[0];
    float ob = wlin * h2n[1];
    #pragma unroll
    for (int m = 32; m > 0; m >>= 1) {
      oa += __shfl_xor(oa, m, 64);
      ob += __shfl_xor(ob, m, 64);
    }
    const float out0 = oa + bl;
    const float out1 = ob + bl;
    fb[0] = out0; fb[1] = out1;

    if (lane == 0) {
      out[(baseb + 2 * w) * TTOT + t]     = out0;
      out[(baseb + 2 * w + 1) * TTOT + t] = out1;
    }
    if (active) {
      h2s[w][0][lane] = h2n[0];
      h2s[w][1][lane] = h2n[1];
    }
    __syncthreads();
  }
}

extern "C" void kernel_launch(void* const* d_in, const int* in_sizes, int n_in,
                              void* d_out, int out_size, void* d_ws, size_t ws_size,
                              hipStream_t stream) {
  const float* inp  = (const float*)d_in[0];
  const float* Wih1 = (const float*)d_in[1];
  const float* bih1 = (const float*)d_in[2];
  const float* Whh1 = (const float*)d_in[3];
  const float* bhh1 = (const float*)d_in[4];
  const float* Wih2 = (const float*)d_in[5];
  const float* bih2 = (const float*)d_in[6];
  const float* Whh2 = (const float*)d_in[7];
  const float* bhh2 = (const float*)d_in[8];
  const float* Wlin = (const float*)d_in[9];
  const float* blin = (const float*)d_in[10];
  float* outp = (float*)d_out;

  lstm2_kernel<<<BATCH / BPB, THREADS, 0, stream>>>(
      inp, Wih1, bih1, Whh1, bhh1, Wih2, bih2, Whh2, bhh2, Wlin, blin, outp);
}